// Round 7
// baseline (1989.419 us; speedup 1.0000x reference)
//
#include <hip/hip_runtime.h>
#include <cstdint>
#include <cstddef>

#define NG     1000
#define NPER   100
#define EPER   1600
#define NNODES (NG*NPER)
#define NEDGES (NG*EPER)
#define HID    128
#define LAT    385
#define FST    388   // padded f32 row stride for top rows (float4-aligned)
#define KTOP   40
#define CHG    200   // graphs per chunk
#define NCHUNK 5
#define CHN    (CHG*NPER)        // nodes per chunk (20,000)
#define GEMM_BLOCKS (CHN/16)     // 1250

// ---------------- preprocessing ----------------
__global__ void k_deg(const int* __restrict__ dst, int* __restrict__ deg) {
  int e = blockIdx.x*blockDim.x + threadIdx.x;
  if (e < NEDGES) atomicAdd(&deg[dst[e]], 1);
}

__global__ void k_dinv64(const int* __restrict__ deg, double* __restrict__ dinv) {
  int i = blockIdx.x*blockDim.x + threadIdx.x;
  if (i < NNODES) {
    int d = deg[i];
    dinv[i] = (d > 0) ? 1.0/sqrt((double)d) : 0.0;
  }
}

__global__ __launch_bounds__(128)
void k_csr(const int* __restrict__ ei0, const int* __restrict__ ei1,
           const int* __restrict__ deg,
           int* __restrict__ rowstart, int* __restrict__ csr_s) {
  int g = blockIdx.x;
  int t = threadIdx.x;
  __shared__ int lstart[NPER];
  __shared__ int cursor[NPER];
  __shared__ int ldeg[NPER];
  if (t < NPER) ldeg[t] = deg[g*NPER + t];
  __syncthreads();
  if (t == 0) {
    int run = 0;
    for (int i = 0; i < NPER; ++i) { lstart[i] = run; run += ldeg[i]; }
  }
  __syncthreads();
  if (t < NPER) { rowstart[g*NPER + t] = lstart[t]; cursor[t] = lstart[t]; }
  __syncthreads();
  for (int e = t; e < EPER; e += 128) {
    int ge = g*EPER + e;
    int s = ei0[ge], d = ei1[ge];
    int slot = atomicAdd(&cursor[d - g*NPER], 1);
    csr_s[(size_t)g*EPER + slot] = s - g*NPER;
  }
}

// ---------------- f64 GEMM: hW[n][c] = sum_k h_in[n][k] * W[k][c] ----------------
// No LDS. Block = 16 nodes x 128 ch, 256 threads: cq = ch-quad (0..31), ng (0..7).
// Thread: 2 nodes (ng, ng+8) x 4 ch. Grid = CHN/16 blocks -> fills the chip.
template<bool L0>
__global__ __launch_bounds__(256)
void k_gemm64(const double* __restrict__ h_in,
              const int* __restrict__ z, const float* __restrict__ ztab,
              const float* __restrict__ x,
              const float* __restrict__ W,
              double* __restrict__ hW, int nofs) {
  int t  = threadIdx.x;
  int cq = t & 31;
  int ng = t >> 5;
  int c0 = cq*4;
  int n0 = blockIdx.x*16 + ng;   // chunk-local node, n1 = n0+8
  int n1 = n0 + 8;

  double a00=0,a01=0,a02=0,a03=0;   // node0, ch c0..c0+3
  double a10=0,a11=0,a12=0,a13=0;   // node1

  // ---- phase A: k = 0..127 (ztab rows for L0, h_in otherwise) ----
  {
    const float  *zr0, *zr1;
    const double *r0, *r1;
    if (L0) {
      zr0 = ztab + (size_t)z[nofs + n0]*HID;
      zr1 = ztab + (size_t)z[nofs + n1]*HID;
    } else {
      r0 = h_in + (size_t)n0*HID;
      r1 = h_in + (size_t)n1*HID;
    }
    #pragma unroll 2
    for (int k = 0; k < 128; k += 2) {
      float4 wa = *(const float4*)&W[(k  )*HID + c0];
      float4 wb = *(const float4*)&W[(k+1)*HID + c0];
      double h0, h1;
      if (L0) { float2 hf = *(const float2*)&zr0[k]; h0 = (double)hf.x; h1 = (double)hf.y; }
      else    { double2 hd = *(const double2*)&r0[k]; h0 = hd.x; h1 = hd.y; }
      a00 = fma(h0,(double)wa.x,a00); a00 = fma(h1,(double)wb.x,a00);
      a01 = fma(h0,(double)wa.y,a01); a01 = fma(h1,(double)wb.y,a01);
      a02 = fma(h0,(double)wa.z,a02); a02 = fma(h1,(double)wb.z,a02);
      a03 = fma(h0,(double)wa.w,a03); a03 = fma(h1,(double)wb.w,a03);
      if (L0) { float2 hf = *(const float2*)&zr1[k]; h0 = (double)hf.x; h1 = (double)hf.y; }
      else    { double2 hd = *(const double2*)&r1[k]; h0 = hd.x; h1 = hd.y; }
      a10 = fma(h0,(double)wa.x,a10); a10 = fma(h1,(double)wb.x,a10);
      a11 = fma(h0,(double)wa.y,a11); a11 = fma(h1,(double)wb.y,a11);
      a12 = fma(h0,(double)wa.z,a12); a12 = fma(h1,(double)wb.z,a12);
      a13 = fma(h0,(double)wa.w,a13); a13 = fma(h1,(double)wb.w,a13);
    }
  }
  // ---- phase B (L0 only): k = 0..127 of x with W rows 128..255 ----
  if (L0) {
    const float* xr0 = x + (size_t)(nofs + n0)*HID;
    const float* xr1 = x + (size_t)(nofs + n1)*HID;
    const float* Wx = W + 128*HID;
    #pragma unroll 2
    for (int k = 0; k < 128; k += 2) {
      float4 wa = *(const float4*)&Wx[(k  )*HID + c0];
      float4 wb = *(const float4*)&Wx[(k+1)*HID + c0];
      float2 hf = *(const float2*)&xr0[k];
      double h0 = (double)hf.x, h1 = (double)hf.y;
      a00 = fma(h0,(double)wa.x,a00); a00 = fma(h1,(double)wb.x,a00);
      a01 = fma(h0,(double)wa.y,a01); a01 = fma(h1,(double)wb.y,a01);
      a02 = fma(h0,(double)wa.z,a02); a02 = fma(h1,(double)wb.z,a02);
      a03 = fma(h0,(double)wa.w,a03); a03 = fma(h1,(double)wb.w,a03);
      hf = *(const float2*)&xr1[k];
      h0 = (double)hf.x; h1 = (double)hf.y;
      a10 = fma(h0,(double)wa.x,a10); a10 = fma(h1,(double)wb.x,a10);
      a11 = fma(h0,(double)wa.y,a11); a11 = fma(h1,(double)wb.y,a11);
      a12 = fma(h0,(double)wa.z,a12); a12 = fma(h1,(double)wb.z,a12);
      a13 = fma(h0,(double)wa.w,a13); a13 = fma(h1,(double)wb.w,a13);
    }
  }
  double2 s;
  s.x=a00; s.y=a01; *(double2*)&hW[(size_t)n0*HID + c0]     = s;
  s.x=a02; s.y=a03; *(double2*)&hW[(size_t)n0*HID + c0 + 2] = s;
  s.x=a10; s.y=a11; *(double2*)&hW[(size_t)n1*HID + c0]     = s;
  s.x=a12; s.y=a13; *(double2*)&hW[(size_t)n1*HID + c0 + 2] = s;
}

// ---------------- aggregation + bias + tanh (f64) --------------------------------
// Block = (graph, 32-ch quarter), 128 threads: cp = ch-pair (0..15), ng (0..7).
// Stages the graph's hW 32-ch slice in LDS (padded stride 34 vs bank aliasing).
__global__ __launch_bounds__(128)
void k_agg64(const double* __restrict__ hW, const float* __restrict__ b,
             const int* __restrict__ rowstart, const int* __restrict__ csr_s,
             const double* __restrict__ dinv,
             double* __restrict__ h_out, int gofs) {
  int gl = blockIdx.x;
  int q  = blockIdx.y;          // ch quarter 0..3
  int g  = gofs + gl;
  int t  = threadIdx.x;
  int cp = t & 15;
  int ng = t >> 4;
  int cq0 = q*32;
  int c0  = cq0 + cp*2;

  __shared__ double hWs[NPER][34];   // 27,200 B (pad 34: banks spread by row)
  __shared__ double dinvL[NPER];

  for (int idx = t; idx < NPER*16; idx += 128) {
    int row = idx >> 4, p = idx & 15;
    double2 v = *(const double2*)&hW[(size_t)(gl*NPER + row)*HID + cq0 + p*2];
    hWs[row][p*2]   = v.x;
    hWs[row][p*2+1] = v.y;
  }
  if (t < NPER) dinvL[t] = dinv[g*NPER + t];
  __syncthreads();

  double bx = (double)b[c0], by = (double)b[c0+1];
  #pragma unroll 1
  for (int i = 0; i < 13; ++i) {
    int n = ng + 8*i;
    if (n < NPER) {
      int gn = g*NPER + n;
      int s0 = rowstart[gn];
      int e1 = (n == NPER-1) ? EPER : rowstart[gn+1];
      double dd = dinvL[n];
      double sx = 0.0, sy = 0.0;
      for (int e = s0; e < e1; ++e) {
        int    s  = csr_s[(size_t)g*EPER + e];
        double nm = dinvL[s]*dd;
        sx = fma(nm, hWs[s][cp*2],   sx);
        sy = fma(nm, hWs[s][cp*2+1], sy);
      }
      size_t o = (size_t)(gl*NPER + n)*HID + c0;
      double2 v; v.x = tanh(sx + bx); v.y = tanh(sy + by);
      *(double2*)&h_out[o] = v;
    }
  }
}

// ---------------- layer 3 (COUT=1) f64 + sort-pool rank selection, chunked --------
__global__ __launch_bounds__(128)
void k_l3sel(const double* __restrict__ h2, const float* __restrict__ W3,
             const float* __restrict__ b3,
             const int* __restrict__ rowstart, const int* __restrict__ csr_s,
             const double* __restrict__ dinv,
             double* __restrict__ key64, int* __restrict__ sel, int gofs) {
  int gl = blockIdx.x, g = gofs + gl, t = threadIdx.x;
  __shared__ double w3d[128];
  __shared__ double hv[NPER];
  __shared__ double key[NPER];
  __shared__ double dinvL[NPER];
  if (t < 128) w3d[t] = (double)W3[t];
  if (t < NPER) dinvL[t] = dinv[g*NPER + t];
  __syncthreads();
  if (t < NPER) {
    const double* row = h2 + (size_t)(gl*NPER + t)*HID;
    double s = 0.0;
    for (int k = 0; k < 128; ++k) s = fma(row[k], w3d[k], s);
    hv[t] = s;
  }
  __syncthreads();
  if (t < NPER) {
    int gn = g*NPER + t;
    int s0 = rowstart[gn];
    int e1 = (t == NPER-1) ? EPER : rowstart[gn+1];
    double dd = dinvL[t];
    double sum = 0.0;
    for (int e = s0; e < e1; ++e) {
      int s = csr_s[(size_t)g*EPER + e];
      sum = fma(dinvL[s]*dd, hv[s], sum);
    }
    double kv = tanh(sum + (double)b3[0]);
    key[t] = kv;
    key64[gl*NPER + t] = kv;
  }
  __syncthreads();
  // stable descending rank == jnp.argsort(-key) with index tie-break
  if (t < NPER) {
    double ki = key[t];
    int rank = 0;
    for (int j = 0; j < NPER; ++j) {
      double kj = key[j];
      rank += ((kj > ki) || (kj == ki && j < t)) ? 1 : 0;
    }
    if (rank < KTOP) sel[g*KTOP + rank] = g*NPER + t;
  }
}

// ---------------- gather top-K rows -> compact f32 [NG][KTOP][FST] ---------------
__global__ __launch_bounds__(256)
void k_gather(const double* __restrict__ h0, const double* __restrict__ h1,
              const double* __restrict__ h2, const double* __restrict__ key64,
              const int* __restrict__ sel, float* __restrict__ topf, int gofs) {
  int gl = blockIdx.x, g = gofs + gl, t = threadIdx.x;
  for (int idx = t; idx < KTOP*97; idx += 256) {
    int k = idx / 97, q = idx - k*97;
    int nloc = sel[g*KTOP + k] - g*NPER;      // 0..99
    size_t row = (size_t)(gl*NPER + nloc)*HID;
    float4 v;
    if (q < 96) {
      const double* src = (q < 32) ? &h0[row + q*4]
                        : (q < 64) ? &h1[row + (q-32)*4]
                                   : &h2[row + (q-64)*4];
      double2 a = *(const double2*)src;
      double2 c = *(const double2*)(src + 2);
      v = make_float4((float)a.x, (float)a.y, (float)c.x, (float)c.y);
    } else {
      v = make_float4((float)key64[gl*NPER + nloc], 0.f, 0.f, 0.f);
    }
    *(float4*)&topf[((size_t)g*KTOP + k)*FST + q*4] = v;
  }
}

// ---------------- head: conv1 + pool + conv2 + MLP ------------------------------
__global__ __launch_bounds__(256)
void k_head(const float* __restrict__ topf,
            const float* __restrict__ cw1, const float* __restrict__ cb1,
            const float* __restrict__ cw2, const float* __restrict__ cb2,
            const float* __restrict__ mW1, const float* __restrict__ mb1,
            const float* __restrict__ mW2, const float* __restrict__ mb2,
            float* __restrict__ out) {
  int g = blockIdx.x, t = threadIdx.x;
  __shared__ float4 top4[KTOP*97];   // 62,080 B
  __shared__ float  c1t[LAT*16];     // 24,640 B (cw1 transposed: [l][f])
  __shared__ float  y1s[16*KTOP];
  __shared__ float  pools[16*20];
  __shared__ float  y2s[512];
  __shared__ float  m1s[128];
  float* top = (float*)top4;

  const float4* tp = (const float4*)topf;
  for (int idx = t; idx < KTOP*97; idx += 256)
    top4[idx] = tp[(size_t)g*KTOP*97 + idx];
  for (int idx = t; idx < LAT*16; idx += 256) {
    int l = idx >> 4, f = idx & 15;
    c1t[idx] = cw1[f*LAT + l];
  }
  __syncthreads();
  // conv1 (kernel=stride=LAT): y1[f][k] = relu(dot(cw1[f], top[k]) + cb1[f])
  for (int idx = t; idx < 16*KTOP; idx += 256) {
    int f = idx & 15, k = idx >> 4;
    float acc = cb1[f];
    for (int l = 0; l < LAT; ++l)
      acc = fmaf(top[k*FST + l], c1t[l*16 + f], acc);
    y1s[f*KTOP + k] = fmaxf(acc, 0.f);
  }
  __syncthreads();
  for (int idx = t; idx < 16*20; idx += 256) {
    int f = idx / 20, tt = idx % 20;
    pools[idx] = fmaxf(y1s[f*KTOP + 2*tt], y1s[f*KTOP + 2*tt + 1]);
  }
  __syncthreads();
  for (int idx = t; idx < 512; idx += 256) {
    int c = idx >> 4, tt = idx & 15;
    float acc = cb2[c];
    #pragma unroll
    for (int f = 0; f < 16; ++f)
      #pragma unroll
      for (int j = 0; j < 5; ++j)
        acc = fmaf(cw2[c*80 + f*5 + j], pools[f*20 + tt + j], acc);
    y2s[idx] = fmaxf(acc, 0.f);
  }
  __syncthreads();
  if (t < 128) {
    float acc = mb1[t];
    for (int i = 0; i < 512; ++i)
      acc = fmaf(y2s[i], mW1[i*128 + t], acc);
    m1s[t] = fmaxf(acc, 0.f);
  }
  __syncthreads();
  if (t < 64) {
    float v = fmaf(m1s[t], mW2[t], m1s[t+64]*mW2[t+64]);
    #pragma unroll
    for (int off = 32; off > 0; off >>= 1) v += __shfl_down(v, off);
    if (t == 0) out[g] = v + mb2[0];
  }
}

// ---------------- launch ----------------
extern "C" void kernel_launch(void* const* d_in, const int* in_sizes, int n_in,
                              void* d_out, int out_size, void* d_ws, size_t ws_size,
                              hipStream_t stream) {
  const float* x    = (const float*)d_in[0];
  const int*   z    = (const int*)  d_in[1];
  const int*   ei   = (const int*)  d_in[2];
  // d_in[3] = batch (unused; graphs are contiguous by construction)
  const float* ztab = (const float*)d_in[4];
  const float* W0   = (const float*)d_in[5];
  const float* b0   = (const float*)d_in[6];
  const float* W1   = (const float*)d_in[7];
  const float* b1   = (const float*)d_in[8];
  const float* W2   = (const float*)d_in[9];
  const float* b2   = (const float*)d_in[10];
  const float* W3   = (const float*)d_in[11];
  const float* b3   = (const float*)d_in[12];
  const float* cw1  = (const float*)d_in[13];
  const float* cb1  = (const float*)d_in[14];
  const float* cw2  = (const float*)d_in[15];
  const float* cb2  = (const float*)d_in[16];
  const float* mW1  = (const float*)d_in[17];
  const float* mb1  = (const float*)d_in[18];
  const float* mW2  = (const float*)d_in[19];
  const float* mb2  = (const float*)d_in[20];
  float* out = (float*)d_out;

  char* ws = (char*)d_ws;
  size_t off = 0;
  auto alloc = [&](size_t bytes) {
    void* p = ws + off;
    off = (off + bytes + 255) & ~(size_t)255;
    return p;
  };
  int*    deg      = (int*)   alloc((size_t)NNODES*4);       //  0.4 MB
  double* dinv     = (double*)alloc((size_t)NNODES*8);       //  0.8 MB
  int*    rowstart = (int*)   alloc((size_t)NNODES*4);       //  0.4 MB
  int*    csr_s    = (int*)   alloc((size_t)NEDGES*4);       //  6.4 MB
  int*    sel      = (int*)   alloc((size_t)NG*KTOP*4);      //  0.16 MB
  double* key64    = (double*)alloc((size_t)CHN*8);          //  0.16 MB
  double* h0       = (double*)alloc((size_t)CHN*HID*8);      // 20.5 MB
  double* h1       = (double*)alloc((size_t)CHN*HID*8);      // 20.5 MB
  double* h2       = (double*)alloc((size_t)CHN*HID*8);      // 20.5 MB
  double* hWb      = (double*)alloc((size_t)CHN*HID*8);      // 20.5 MB
  float*  topf     = (float*) alloc((size_t)NG*KTOP*FST*4);  // 62.1 MB
  (void)ws_size;                                             // ~152 MB total

  const int* ei0 = ei;            // src
  const int* ei1 = ei + NEDGES;   // dst

  hipMemsetAsync(deg, 0, (size_t)NNODES*4, stream);
  k_deg   <<<(NEDGES+255)/256, 256, 0, stream>>>(ei1, deg);
  k_dinv64<<<(NNODES+255)/256, 256, 0, stream>>>(deg, dinv);
  k_csr   <<<NG, 128, 0, stream>>>(ei0, ei1, deg, rowstart, csr_s);

  for (int c = 0; c < NCHUNK; ++c) {
    int gofs = c*CHG;
    int nofs = gofs*NPER;
    dim3 gB(CHG, 4);
    k_gemm64<true ><<<GEMM_BLOCKS, 256, 0, stream>>>(h0, z, ztab, x, W0, hWb, nofs);
    k_agg64 <<<gB, 128, 0, stream>>>(hWb, b0, rowstart, csr_s, dinv, h0, gofs);
    k_gemm64<false><<<GEMM_BLOCKS, 256, 0, stream>>>(h0, z, ztab, x, W1, hWb, nofs);
    k_agg64 <<<gB, 128, 0, stream>>>(hWb, b1, rowstart, csr_s, dinv, h1, gofs);
    k_gemm64<false><<<GEMM_BLOCKS, 256, 0, stream>>>(h1, z, ztab, x, W2, hWb, nofs);
    k_agg64 <<<gB, 128, 0, stream>>>(hWb, b2, rowstart, csr_s, dinv, h2, gofs);
    k_l3sel <<<CHG, 128, 0, stream>>>(h2, W3, b3, rowstart, csr_s, dinv, key64, sel, gofs);
    k_gather<<<CHG, 256, 0, stream>>>(h0, h1, h2, key64, sel, topf, gofs);
  }
  k_head<<<NG, 256, 0, stream>>>(topf, cw1, cb1, cw2, cb2, mW1, mb1, mW2, mb2, out);
}

// Round 8
// 1728.094 us; speedup vs baseline: 1.1512x; 1.1512x over previous
//
#include <hip/hip_runtime.h>
#include <cstdint>
#include <cstddef>

#define NG     1000
#define NPER   100
#define EPER   1600
#define NNODES (NG*NPER)
#define NEDGES (NG*EPER)
#define HID    128
#define LAT    385
#define FST    388   // padded f32 row stride for top rows (float4-aligned)
#define KTOP   40
#define CHG    250   // graphs per chunk
#define NCHUNK 4
#define CHN    (CHG*NPER)

// ---------------- preprocessing ----------------
__global__ void k_deg(const int* __restrict__ dst, int* __restrict__ deg) {
  int e = blockIdx.x*blockDim.x + threadIdx.x;
  if (e < NEDGES) atomicAdd(&deg[dst[e]], 1);
}

__global__ void k_dinv64(const int* __restrict__ deg, double* __restrict__ dinv) {
  int i = blockIdx.x*blockDim.x + threadIdx.x;
  if (i < NNODES) {
    int d = deg[i];
    dinv[i] = (d > 0) ? 1.0/sqrt((double)d) : 0.0;
  }
}

__global__ __launch_bounds__(128)
void k_csr(const int* __restrict__ ei0, const int* __restrict__ ei1,
           const int* __restrict__ deg,
           int* __restrict__ rowstart, int* __restrict__ csr_s) {
  int g = blockIdx.x;
  int t = threadIdx.x;
  __shared__ int lstart[NPER];
  __shared__ int cursor[NPER];
  __shared__ int ldeg[NPER];
  if (t < NPER) ldeg[t] = deg[g*NPER + t];
  __syncthreads();
  if (t == 0) {
    int run = 0;
    for (int i = 0; i < NPER; ++i) { lstart[i] = run; run += ldeg[i]; }
  }
  __syncthreads();
  if (t < NPER) { rowstart[g*NPER + t] = lstart[t]; cursor[t] = lstart[t]; }
  __syncthreads();
  for (int e = t; e < EPER; e += 128) {
    int ge = g*EPER + e;
    int s = ei0[ge], d = ei1[ge];
    int slot = atomicAdd(&cursor[d - g*NPER], 1);
    csr_s[(size_t)g*EPER + slot] = s - g*NPER;
  }
}

// ---------------- fused GCN layer, f64, 32-ch quarter per block -----------------
// grid (CHG, 4), 256 threads: cp = ch-pair (0..15), ng = node group (0..15),
// 7 nodes per thread (16*7 = 112 >= 100). Edge list staged in LDS (no dependent
// global loads in the aggregation loop).
template<bool L0>
__global__ __launch_bounds__(256, 4)
void k_layer64(const double* __restrict__ h_in,
               const int* __restrict__ z, const float* __restrict__ ztab,
               const float* __restrict__ x,
               const float* __restrict__ W, const float* __restrict__ b,
               const int* __restrict__ rowstart, const int* __restrict__ csr_s,
               const double* __restrict__ dinv,
               double* __restrict__ h_out, int gofs) {
  int gl = blockIdx.x;
  int q  = blockIdx.y;
  int g  = gofs + gl;
  int t  = threadIdx.x;
  int cp = t & 15;
  int ng = t >> 4;
  int c0 = q*32 + cp*2;

  __shared__ double hWs[NPER][34];  // 27,200 B (pad 34 spreads banks per row)
  __shared__ double dinvL[NPER];    //    800 B
  __shared__ int    rsL[NPER+1];
  __shared__ int    edgeL[EPER];    //  6,400 B

  // stage graph topology early (consumed after the barrier)
  for (int e = t; e < EPER; e += 256) edgeL[e] = csr_s[(size_t)g*EPER + e];
  if (t < NPER) { dinvL[t] = dinv[g*NPER + t]; rsL[t] = rowstart[g*NPER + t]; }
  else if (t == NPER) rsL[NPER] = EPER;

  int nid[7];
  #pragma unroll
  for (int i = 0; i < 7; ++i) { int n = ng + 16*i; nid[i] = (n < NPER) ? n : (NPER-1); }

  double ax[7], ay[7];
  #pragma unroll
  for (int i = 0; i < 7; ++i) { ax[i] = 0.0; ay[i] = 0.0; }

  // ---- GEMM phase A: k = 0..127 (ztab rows for L0, previous layer otherwise) ----
  {
    const double* rp[7];
    const float*  rpf[7];
    #pragma unroll
    for (int i = 0; i < 7; ++i) {
      if (L0) rpf[i] = ztab + (size_t)z[g*NPER + nid[i]]*HID;
      else    rp[i]  = h_in + (size_t)(gl*NPER + nid[i])*HID;
    }
    for (int k = 0; k < 128; k += 2) {
      float2 wa = *(const float2*)&W[(k  )*HID + c0];
      float2 wb = *(const float2*)&W[(k+1)*HID + c0];
      double wax = (double)wa.x, way = (double)wa.y;
      double wbx = (double)wb.x, wby = (double)wb.y;
      #pragma unroll
      for (int i = 0; i < 7; ++i) {
        double h0v, h1v;
        if (L0) { float2 hf = *(const float2*)&rpf[i][k]; h0v = (double)hf.x; h1v = (double)hf.y; }
        else    { double2 hd = *(const double2*)&rp[i][k]; h0v = hd.x; h1v = hd.y; }
        ax[i] = fma(h0v, wax, ax[i]); ax[i] = fma(h1v, wbx, ax[i]);
        ay[i] = fma(h0v, way, ay[i]); ay[i] = fma(h1v, wby, ay[i]);
      }
    }
  }
  // ---- GEMM phase B (L0 only): x rows with W rows 128..255 ----
  if (L0) {
    const float* rpf[7];
    #pragma unroll
    for (int i = 0; i < 7; ++i) rpf[i] = x + (size_t)(g*NPER + nid[i])*HID;
    const float* Wx = W + 128*HID;
    for (int k = 0; k < 128; k += 2) {
      float2 wa = *(const float2*)&Wx[(k  )*HID + c0];
      float2 wb = *(const float2*)&Wx[(k+1)*HID + c0];
      double wax = (double)wa.x, way = (double)wa.y;
      double wbx = (double)wb.x, wby = (double)wb.y;
      #pragma unroll
      for (int i = 0; i < 7; ++i) {
        float2 hf = *(const float2*)&rpf[i][k];
        double h0v = (double)hf.x, h1v = (double)hf.y;
        ax[i] = fma(h0v, wax, ax[i]); ax[i] = fma(h1v, wbx, ax[i]);
        ay[i] = fma(h0v, way, ay[i]); ay[i] = fma(h1v, wby, ay[i]);
      }
    }
  }
  #pragma unroll
  for (int i = 0; i < 7; ++i) {
    int n = ng + 16*i;
    if (n < NPER) { hWs[n][cp*2] = ax[i]; hWs[n][cp*2+1] = ay[i]; }
  }
  __syncthreads();

  // ---- aggregation (LDS-only) + bias + tanh, f64 ----
  double bx = (double)b[c0], by = (double)b[c0+1];
  #pragma unroll 1
  for (int i = 0; i < 7; ++i) {
    int n = ng + 16*i;
    if (n < NPER) {
      int s0 = rsL[n], e1 = rsL[n+1];
      double dd = dinvL[n];
      double sx = 0.0, sy = 0.0;
      for (int e = s0; e < e1; ++e) {
        int    s  = edgeL[e];
        double nm = dinvL[s]*dd;
        sx = fma(nm, hWs[s][cp*2],   sx);
        sy = fma(nm, hWs[s][cp*2+1], sy);
      }
      size_t o = (size_t)(gl*NPER + n)*HID + c0;
      double2 v; v.x = tanh(sx + bx); v.y = tanh(sy + by);
      *(double2*)&h_out[o] = v;
    }
  }
}

// ---------------- layer 3 + rank + gather fused (per-graph block) ----------------
__global__ __launch_bounds__(128)
void k_l3g(const double* __restrict__ h0, const double* __restrict__ h1,
           const double* __restrict__ h2,
           const float* __restrict__ W3, const float* __restrict__ b3,
           const int* __restrict__ rowstart, const int* __restrict__ csr_s,
           const double* __restrict__ dinv,
           float* __restrict__ topf, int gofs) {
  int gl = blockIdx.x, g = gofs + gl, t = threadIdx.x;
  __shared__ double w3d[128];
  __shared__ double hv[NPER];
  __shared__ double key[NPER];
  __shared__ double dinvL[NPER];
  __shared__ int    rsL[NPER+1];
  __shared__ int    edgeL[EPER];
  __shared__ int    selL[KTOP];
  for (int e = t; e < EPER; e += 128) edgeL[e] = csr_s[(size_t)g*EPER + e];
  w3d[t] = (double)W3[t];
  if (t < NPER) { dinvL[t] = dinv[g*NPER + t]; rsL[t] = rowstart[g*NPER + t]; }
  else if (t == NPER) rsL[NPER] = EPER;
  __syncthreads();
  if (t < NPER) {
    const double* row = h2 + (size_t)(gl*NPER + t)*HID;
    double s = 0.0;
    for (int k = 0; k < 128; ++k) s = fma(row[k], w3d[k], s);
    hv[t] = s;
  }
  __syncthreads();
  if (t < NPER) {
    double dd = dinvL[t];
    double sum = 0.0;
    int s0 = rsL[t], e1 = rsL[t+1];
    for (int e = s0; e < e1; ++e) {
      int s = edgeL[e];
      sum = fma(dinvL[s]*dd, hv[s], sum);
    }
    key[t] = tanh(sum + (double)b3[0]);
  }
  __syncthreads();
  // stable descending rank == jnp.argsort(-key) with index tie-break
  if (t < NPER) {
    double ki = key[t];
    int rank = 0;
    for (int j = 0; j < NPER; ++j) {
      double kj = key[j];
      rank += ((kj > ki) || (kj == ki && j < t)) ? 1 : 0;
    }
    if (rank < KTOP) selL[rank] = t;
  }
  __syncthreads();
  // gather top-K rows -> compact f32 [g][KTOP][FST]
  for (int idx = t; idx < KTOP*97; idx += 128) {
    int k = idx / 97, qq = idx - k*97;
    int nloc = selL[k];
    size_t row = (size_t)(gl*NPER + nloc)*HID;
    float4 v;
    if (qq < 96) {
      const double* src = (qq < 32) ? &h0[row + qq*4]
                        : (qq < 64) ? &h1[row + (qq-32)*4]
                                    : &h2[row + (qq-64)*4];
      double2 a = *(const double2*)src;
      double2 c = *(const double2*)(src + 2);
      v = make_float4((float)a.x, (float)a.y, (float)c.x, (float)c.y);
    } else {
      v = make_float4((float)key[nloc], 0.f, 0.f, 0.f);
    }
    *(float4*)&topf[((size_t)g*KTOP + k)*FST + qq*4] = v;
  }
}

// ---------------- head: conv1 + pool + conv2 + MLP (topf read from global) -------
__global__ __launch_bounds__(256)
void k_head(const float* __restrict__ topf,
            const float* __restrict__ cw1, const float* __restrict__ cb1,
            const float* __restrict__ cw2, const float* __restrict__ cb2,
            const float* __restrict__ mW1, const float* __restrict__ mb1,
            const float* __restrict__ mW2, const float* __restrict__ mb2,
            float* __restrict__ out) {
  int g = blockIdx.x, t = threadIdx.x;
  __shared__ float c1t[LAT*16];     // 24,640 B (cw1 transposed: [l][f])
  __shared__ float y1s[16*KTOP];
  __shared__ float pools[16*20];
  __shared__ float y2s[512];
  __shared__ float m1s[128];

  for (int idx = t; idx < LAT*16; idx += 256) {
    int l = idx >> 4, f = idx & 15;
    c1t[idx] = cw1[f*LAT + l];
  }
  __syncthreads();
  const float* tg = topf + (size_t)g*KTOP*FST;
  // conv1 (kernel=stride=LAT): y1[f][k] = relu(dot(cw1[f], top[k]) + cb1[f])
  for (int idx = t; idx < 16*KTOP; idx += 256) {
    int f = idx & 15, k = idx >> 4;
    const float4* row4 = (const float4*)(tg + (size_t)k*FST);
    float acc = cb1[f];
    for (int l4 = 0; l4 < 96; ++l4) {
      float4 r = row4[l4];
      const float* cc = &c1t[(l4*4)*16 + f];
      acc = fmaf(r.x, cc[0],  acc);
      acc = fmaf(r.y, cc[16], acc);
      acc = fmaf(r.z, cc[32], acc);
      acc = fmaf(r.w, cc[48], acc);
    }
    acc = fmaf(tg[(size_t)k*FST + 384], c1t[384*16 + f], acc);
    y1s[f*KTOP + k] = fmaxf(acc, 0.f);
  }
  __syncthreads();
  for (int idx = t; idx < 16*20; idx += 256) {
    int f = idx / 20, tt = idx % 20;
    pools[idx] = fmaxf(y1s[f*KTOP + 2*tt], y1s[f*KTOP + 2*tt + 1]);
  }
  __syncthreads();
  for (int idx = t; idx < 512; idx += 256) {
    int c = idx >> 4, tt = idx & 15;
    float acc = cb2[c];
    #pragma unroll
    for (int f = 0; f < 16; ++f)
      #pragma unroll
      for (int j = 0; j < 5; ++j)
        acc = fmaf(cw2[c*80 + f*5 + j], pools[f*20 + tt + j], acc);
    y2s[idx] = fmaxf(acc, 0.f);
  }
  __syncthreads();
  if (t < 128) {
    float acc = mb1[t];
    for (int i = 0; i < 512; ++i)
      acc = fmaf(y2s[i], mW1[i*128 + t], acc);
    m1s[t] = fmaxf(acc, 0.f);
  }
  __syncthreads();
  if (t < 64) {
    float v = fmaf(m1s[t], mW2[t], m1s[t+64]*mW2[t+64]);
    #pragma unroll
    for (int off = 32; off > 0; off >>= 1) v += __shfl_down(v, off);
    if (t == 0) out[g] = v + mb2[0];
  }
}

// ---------------- launch ----------------
extern "C" void kernel_launch(void* const* d_in, const int* in_sizes, int n_in,
                              void* d_out, int out_size, void* d_ws, size_t ws_size,
                              hipStream_t stream) {
  const float* x    = (const float*)d_in[0];
  const int*   z    = (const int*)  d_in[1];
  const int*   ei   = (const int*)  d_in[2];
  // d_in[3] = batch (unused; graphs are contiguous by construction)
  const float* ztab = (const float*)d_in[4];
  const float* W0   = (const float*)d_in[5];
  const float* b0   = (const float*)d_in[6];
  const float* W1   = (const float*)d_in[7];
  const float* b1   = (const float*)d_in[8];
  const float* W2   = (const float*)d_in[9];
  const float* b2   = (const float*)d_in[10];
  const float* W3   = (const float*)d_in[11];
  const float* b3   = (const float*)d_in[12];
  const float* cw1  = (const float*)d_in[13];
  const float* cb1  = (const float*)d_in[14];
  const float* cw2  = (const float*)d_in[15];
  const float* cb2  = (const float*)d_in[16];
  const float* mW1  = (const float*)d_in[17];
  const float* mb1  = (const float*)d_in[18];
  const float* mW2  = (const float*)d_in[19];
  const float* mb2  = (const float*)d_in[20];
  float* out = (float*)d_out;

  char* ws = (char*)d_ws;
  size_t off = 0;
  auto alloc = [&](size_t bytes) {
    void* p = ws + off;
    off = (off + bytes + 255) & ~(size_t)255;
    return p;
  };
  int*    deg      = (int*)   alloc((size_t)NNODES*4);       //  0.4 MB
  double* dinv     = (double*)alloc((size_t)NNODES*8);       //  0.8 MB
  int*    rowstart = (int*)   alloc((size_t)NNODES*4);       //  0.4 MB
  int*    csr_s    = (int*)   alloc((size_t)NEDGES*4);       //  6.4 MB
  double* h0       = (double*)alloc((size_t)CHN*HID*8);      // 25.6 MB
  double* h1       = (double*)alloc((size_t)CHN*HID*8);      // 25.6 MB
  double* h2       = (double*)alloc((size_t)CHN*HID*8);      // 25.6 MB
  float*  topf     = (float*) alloc((size_t)NG*KTOP*FST*4);  // 62.1 MB
  (void)ws_size;                                             // ~147 MB total

  const int* ei0 = ei;            // src
  const int* ei1 = ei + NEDGES;   // dst

  hipMemsetAsync(deg, 0, (size_t)NNODES*4, stream);
  k_deg   <<<(NEDGES+255)/256, 256, 0, stream>>>(ei1, deg);
  k_dinv64<<<(NNODES+255)/256, 256, 0, stream>>>(deg, dinv);
  k_csr   <<<NG, 128, 0, stream>>>(ei0, ei1, deg, rowstart, csr_s);

  for (int c = 0; c < NCHUNK; ++c) {
    int gofs = c*CHG;
    dim3 lg(CHG, 4);
    k_layer64<true ><<<lg, 256, 0, stream>>>(h0, z, ztab, x, W0, b0, rowstart, csr_s, dinv, h0, gofs);
    k_layer64<false><<<lg, 256, 0, stream>>>(h0, z, ztab, x, W1, b1, rowstart, csr_s, dinv, h1, gofs);
    k_layer64<false><<<lg, 256, 0, stream>>>(h1, z, ztab, x, W2, b2, rowstart, csr_s, dinv, h2, gofs);
    k_l3g   <<<CHG, 128, 0, stream>>>(h0, h1, h2, W3, b3, rowstart, csr_s, dinv, topf, gofs);
  }
  k_head<<<NG, 256, 0, stream>>>(topf, cw1, cb1, cw2, cb2, mW1, mb1, mW2, mb2, out);
}